// Round 5
// baseline (401.992 us; speedup 1.0000x reference)
//
#include <hip/hip_runtime.h>
#include <stdint.h>

// Attention forward, B=4 S=2048 E=1024 H=16 D=64, causal. Outputs: o fp32 then
// attn.mean(heads) fp32.
//
// R10: (a) k_attnz: Ps XOR swizzle REMOVED — with the [72] pad (row stride
//      = 4 banks mod 32) the natural layout is conflict-floor for both b64
//      writes and b128 reads; R9's XOR was the 2.38e7 conflicts. (b) fused
//      halves: one kt sweep [0, 32-2qx) stages each K/V tile once, feeds
//      half1 always + half0 while kt in range; co-resident pairs (b, b+2)
//      get complementary qx -> uniform 50 tiles per CU. (c) k_mean: Q tile
//      dropped from LDS (each wave only reads its own 16 rows) -> Q frags
//      prefetched to registers per head; LDS 41KB -> 22.5KB.

#define BB 4
#define SS 2048
#define EE 1024
#define HH 16
#define DD 64
#define MTOT (BB*SS)          // 8192
#define HD (HH*DD)            // 1024
#define QKV_ELEMS ((size_t)MTOT*HD)

typedef float f32x4 __attribute__((ext_vector_type(4)));
typedef short bf16x8 __attribute__((ext_vector_type(8)));

#define GLL(g, l) __builtin_amdgcn_global_load_lds( \
    (const __attribute__((address_space(1))) void*)(g), \
    (__attribute__((address_space(3))) void*)(l), 16, 0, 0)

__device__ __forceinline__ short f2bf(float f) {
    unsigned u = __builtin_bit_cast(unsigned, f);
    u += 0x7FFFu + ((u >> 16) & 1u);   // RNE
    return (short)(u >> 16);
}

// ---------------- prep 1: x fp32 -> bf16 ----------------
__global__ __launch_bounds__(256) void k_xcast(const float* __restrict__ x,
                                               short* __restrict__ xbf) {
    int i = blockIdx.x*256 + threadIdx.x;
    float4 f = ((const float4*)x)[i];
    short4 s; s.x=f2bf(f.x); s.y=f2bf(f.y); s.z=f2bf(f.z); s.w=f2bf(f.w);
    ((short4*)xbf)[i] = s;
}

// ---------------- prep 2: W -> bf16, transposed to [n][k] ----------------
__global__ __launch_bounds__(256) void k_wprep(const float* __restrict__ wq,
        const float* __restrict__ wk, const float* __restrict__ wv,
        const float* __restrict__ wo, short* __restrict__ wtq,
        short* __restrict__ wto) {
    __shared__ short Tl[64][72];
    int t = threadIdx.x, x = blockIdx.x, y = blockIdx.y;
    int r4 = t >> 2, c4 = (t & 3) << 4;
    if (y < 48) {
        int which = y >> 4, h = y & 15, e0 = x*64;
        const float* src = (which==0?wq:which==1?wk:wv) + (size_t)h*EE*DD;
        const float* p = src + (size_t)(e0 + r4)*DD + c4;
        #pragma unroll
        for (int j = 0; j < 4; ++j) {
            float4 f = ((const float4*)p)[j];
            Tl[r4][c4+j*4+0]=f2bf(f.x); Tl[r4][c4+j*4+1]=f2bf(f.y);
            Tl[r4][c4+j*4+2]=f2bf(f.z); Tl[r4][c4+j*4+3]=f2bf(f.w);
        }
        __syncthreads();
        size_t nrow = ((size_t)(which*16 + h))*64 + r4;   // d = r4
        #pragma unroll
        for (int i = 0; i < 16; ++i)
            wtq[nrow*1024 + e0 + c4 + i] = Tl[c4+i][r4];
    } else {
        int h = y - 48, e0 = x*64;
        const float* src = wo + (size_t)h*DD*EE;          // [d][e]
        const float* p = src + (size_t)r4*EE + e0 + c4;   // d = r4
        #pragma unroll
        for (int j = 0; j < 4; ++j) {
            float4 f = ((const float4*)p)[j];
            Tl[r4][c4+j*4+0]=f2bf(f.x); Tl[r4][c4+j*4+1]=f2bf(f.y);
            Tl[r4][c4+j*4+2]=f2bf(f.z); Tl[r4][c4+j*4+3]=f2bf(f.w);
        }
        __syncthreads();
        #pragma unroll
        for (int i = 0; i < 16; ++i)
            wto[(size_t)(e0 + r4)*1024 + h*64 + c4 + i] = Tl[c4+i][r4];
    }
}

// ---------------- kernel 1: QKV projection, m97-style ----------------
// grid (64, 24): 128x128 tile, BK=64. Q,K stored [b*S+pos][h*64+d];
// V stored PRE-TRANSPOSED [b][h*64+d][pos].
__global__ __launch_bounds__(256) void k_proj(const short* __restrict__ xbf,
        const short* __restrict__ wtq, short* __restrict__ qkv) {
    __shared__ short As[128*64];
    __shared__ short Bs[128*64];
    int t = threadIdx.x;
    int m0 = blockIdx.x*128, n0 = blockIdx.y*128;
    int lane = t & 63, l15 = lane & 15, quad = lane >> 4;
    int wm = (t>>6) >> 1, wn = (t>>6) & 1;
    f32x4 acc[4][4];
    #pragma unroll
    for (int i=0;i<4;++i)
        #pragma unroll
        for (int c=0;c<4;++c) acc[i][c] = (f32x4){0,0,0,0};

    for (int k0 = 0; k0 < EE; k0 += 64) {
        __syncthreads();
        #pragma unroll
        for (int j = 0; j < 4; ++j) {
            int c = j*256 + t;
            int row = c >> 3, cg = c & 7;
            GLL(xbf + (size_t)(m0+row)*EE + k0 + cg*8, &As[(j*256 + (t & 192))*8]);
            GLL(wtq + (size_t)(n0+row)*EE + k0 + cg*8, &Bs[(j*256 + (t & 192))*8]);
        }
        __syncthreads();
        #pragma unroll
        for (int kp = 0; kp < 64; kp += 32)
            #pragma unroll
            for (int i = 0; i < 4; ++i) {
                bf16x8 a = *(const bf16x8*)&As[(wm*64 + i*16 + l15)*64 + kp + quad*8];
                #pragma unroll
                for (int c = 0; c < 4; ++c) {
                    bf16x8 b = *(const bf16x8*)&Bs[(wn*64 + c*16 + l15)*64 + kp + quad*8];
                    acc[i][c] = __builtin_amdgcn_mfma_f32_16x16x32_bf16(a, b, acc[i][c], 0, 0, 0);
                }
            }
    }
    short* vt = qkv + 2*QKV_ELEMS;
    #pragma unroll
    for (int i = 0; i < 4; ++i)
        #pragma unroll
        for (int c = 0; c < 4; ++c) {
            int n = n0 + wn*64 + c*16 + l15;
            int row = m0 + wm*64 + i*16 + quad*4;
            if (n < 2048) {          // Q or K: [region][b*S+pos][h*64+d]
                #pragma unroll
                for (int r = 0; r < 4; ++r)
                    qkv[(size_t)(n>>10)*QKV_ELEMS + (size_t)(row+r)*HD + (n & 1023)] =
                        f2bf(acc[i][c][r]);
            } else {                 // V: [b][h*64+d][pos], pos contiguous in r
                short4 s4;
                s4.x = f2bf(acc[i][c][0]); s4.y = f2bf(acc[i][c][1]);
                s4.z = f2bf(acc[i][c][2]); s4.w = f2bf(acc[i][c][3]);
                int bb_ = row >> 11, pos = row & 2047;
                *(short4*)&vt[((size_t)bb_*HD + (n - 2048))*SS + pos] = s4;
            }
        }
}

// ---------- kernel 2: z = softmax(QK^T/8) V, no-max; exports c2=log2(l) ----------
// grid (8, 16, 4): fused halves {qxa, 15-qxa}: ONE kt sweep [0, 32-2qxa)
// stages each K/V tile once; half1 accumulates always, half0 while in range.
// qxa = (b>=2) ? 7-bx : bx  -> co-resident pair (id, id+256) sums to 50 tiles.
// Swapped QK^T (mfma(K,Q)) -> packed b64 P-writes; Ps NATURAL layout ([72]
// pad's 4-bank row offset spreads banks; no XOR).
__global__ __launch_bounds__(256) void k_attnz(const short* __restrict__ qws,
        const short* __restrict__ kws, const short* __restrict__ vtg,
        short* __restrict__ zws, float* __restrict__ c2ws) {
    __shared__ short Ks[64][72];
    __shared__ short Vt[64][72];
    __shared__ short Ps[4][32][72];   // per-wave P tile (no barrier needed)
    int t = threadIdx.x;
    int h = blockIdx.y, b = blockIdx.z;
    int bx = blockIdx.x;
    int qxa = (b >= 2) ? (7 - bx) : bx;
    int q0a = qxa*128, q0b = (15 - qxa)*128;
    int nk  = 32 - 2*qxa;             // = q0b/64 + 2 (half1's full range)
    int w = t>>6, lane = t&63, l15 = lane&15, quad = lane>>4;
    int sr = t>>2, sc = (t&3)<<4;

    const short* ksrc = kws + (size_t)(b*SS + sr)*HD + h*DD + sc;
    const short* vsrc = vtg + ((size_t)b*HD + h*DD + sr)*SS + sc;

    bf16x8 qA[2][2], qB[2][2];        // Q fragments, both halves, loop-invariant
    #pragma unroll
    for (int mf=0; mf<2; ++mf)
        #pragma unroll
        for (int kp=0; kp<2; ++kp) {
            qA[mf][kp] = *(const bf16x8*)(qws +
                (size_t)(b*SS + q0a + w*32 + mf*16 + l15)*HD + h*DD + kp*32 + quad*8);
            qB[mf][kp] = *(const bf16x8*)(qws +
                (size_t)(b*SS + q0b + w*32 + mf*16 + l15)*HD + h*DD + kp*32 + quad*8);
        }

    f32x4 azA[2][4], azB[2][4], alA[2], alB[2];
    #pragma unroll
    for (int mf=0;mf<2;++mf) {
        alA[mf] = (f32x4){0,0,0,0}; alB[mf] = (f32x4){0,0,0,0};
        #pragma unroll
        for (int c=0;c<4;++c) { azA[mf][c] = (f32x4){0,0,0,0}; azB[mf][c] = (f32x4){0,0,0,0}; }
    }
    bf16x8 ones;
    #pragma unroll
    for (int i=0;i<8;++i) ones[i] = (short)0x3F80;   // bf16 1.0
    const float SC = 0.125f * 1.4426950408889634f;
    int qmaxA = q0a + w*32 + 31, qmaxB = q0b + w*32 + 31;

    uint4 pk0 = ((const uint4*)ksrc)[0], pk1 = ((const uint4*)ksrc)[1];
    uint4 pv0 = ((const uint4*)vsrc)[0], pv1 = ((const uint4*)vsrc)[1];

// one k-tile of online attention for one half (macro keeps static indexing)
#define TILE(QF, AZ, AL, Q0, QMAX)                                             \
    if (k0 <= (QMAX)) {                                                        \
        f32x4 s_[2][4];                                                        \
        _Pragma("unroll")                                                      \
        for (int mf=0;mf<2;++mf)                                               \
            _Pragma("unroll")                                                  \
            for (int c=0;c<4;++c) s_[mf][c] = (f32x4){0,0,0,0};                \
        __builtin_amdgcn_s_setprio(1);                                         \
        _Pragma("unroll")                                                      \
        for (int c=0;c<4;++c)                                                  \
            _Pragma("unroll")                                                  \
            for (int kp=0;kp<2;++kp) {                                         \
                bf16x8 aK = *(const bf16x8*)&Ks[c*16+l15][kp*32+quad*8];       \
                s_[0][c] = __builtin_amdgcn_mfma_f32_16x16x32_bf16(aK, QF[0][kp], s_[0][c], 0, 0, 0); \
                s_[1][c] = __builtin_amdgcn_mfma_f32_16x16x32_bf16(aK, QF[1][kp], s_[1][c], 0, 0, 0); \
            }                                                                  \
        __builtin_amdgcn_s_setprio(0);                                         \
        _Pragma("unroll")                                                      \
        for (int mf=0;mf<2;++mf) {                                             \
            int qg = (Q0) + w*32 + mf*16 + l15;                                \
            _Pragma("unroll")                                                  \
            for (int c=0;c<4;++c) {                                            \
                int kb_ = k0 + c*16 + quad*4;                                  \
                short4 s4;                                                     \
                _Pragma("unroll")                                              \
                for (int r=0;r<4;++r) {                                        \
                    float p_ = (kb_ + r <= qg) ? __builtin_amdgcn_exp2f(s_[mf][c][r]*SC) : 0.0f; \
                    ((short*)&s4)[r] = f2bf(p_);                               \
                }                                                              \
                *(short4*)&Ps[w][mf*16 + l15][c*16 + quad*4] = s4;             \
            }                                                                  \
        }                                                                      \
        __builtin_amdgcn_s_setprio(1);                                         \
        _Pragma("unroll")                                                      \
        for (int kp=0;kp<2;++kp) {                                             \
            bf16x8 pa0 = *(const bf16x8*)&Ps[w][l15][kp*32+quad*8];            \
            bf16x8 pa1 = *(const bf16x8*)&Ps[w][16+l15][kp*32+quad*8];         \
            _Pragma("unroll")                                                  \
            for (int cc=0;cc<4;++cc) {                                         \
                bf16x8 vb = *(const bf16x8*)&Vt[cc*16+l15][kp*32+quad*8];      \
                AZ[0][cc] = __builtin_amdgcn_mfma_f32_16x16x32_bf16(pa0, vb, AZ[0][cc], 0, 0, 0); \
                AZ[1][cc] = __builtin_amdgcn_mfma_f32_16x16x32_bf16(pa1, vb, AZ[1][cc], 0, 0, 0); \
            }                                                                  \
            AL[0] = __builtin_amdgcn_mfma_f32_16x16x32_bf16(pa0, ones, AL[0], 0, 0, 0); \
            AL[1] = __builtin_amdgcn_mfma_f32_16x16x32_bf16(pa1, ones, AL[1], 0, 0, 0); \
        }                                                                      \
        __builtin_amdgcn_s_setprio(0);                                         \
    }

    for (int kt = 0; kt < nk; ++kt) {
        int k0 = kt*64;
        __syncthreads();               // prior compute done reading LDS
        *(uint4*)&Ks[sr][sc]   = pk0;  *(uint4*)&Ks[sr][sc+8] = pk1;
        *(uint4*)&Vt[sr][sc]   = pv0;  *(uint4*)&Vt[sr][sc+8] = pv1;
        __syncthreads();               // tile ready
        if (kt+1 < nk) {               // T14: issue next tile under compute
            const uint4* kn = (const uint4*)(ksrc + (size_t)(k0+64)*HD);
            const uint4* vn = (const uint4*)(vsrc + (k0+64));
            pk0=kn[0]; pk1=kn[1]; pv0=vn[0]; pv1=vn[1];
        }
        TILE(qB, azB, alB, q0b, qmaxB);
        TILE(qA, azA, alA, q0a, qmaxA);
    }
#undef TILE

#define EPI(AZ, AL, Q0)                                                        \
    _Pragma("unroll")                                                          \
    for (int mf=0;mf<2;++mf) {                                                 \
        float il[4];                                                           \
        _Pragma("unroll")                                                      \
        for (int r=0;r<4;++r) il[r] = 1.0f / AL[mf][r];                        \
        _Pragma("unroll")                                                      \
        for (int cc=0;cc<4;++cc)                                               \
            _Pragma("unroll")                                                  \
            for (int r=0;r<4;++r) {                                            \
                int row = (Q0) + w*32 + mf*16 + quad*4 + r;                    \
                zws[(size_t)(b*SS+row)*HD + h*DD + cc*16 + l15] = f2bf(AZ[mf][cc][r]*il[r]); \
            }                                                                  \
        if (l15 == 0) {                                                        \
            size_t base = ((size_t)(b*HH+h))*SS + (Q0) + w*32 + mf*16 + quad*4;\
            _Pragma("unroll")                                                  \
            for (int r=0;r<4;++r)                                              \
                c2ws[base+r] = __log2f(AL[mf][r]);                             \
        }                                                                      \
    }

    EPI(azB, alB, q0b);
    EPI(azA, alA, q0a);
#undef EPI
}

// ---------------- kernel 3: attn mean over heads ----------------
// grid (32, 32, 4). Upper-triangle blocks write zeros. R10: only K staged in
// LDS (each wave reads just its own 16 Q rows -> Q frags prefetched to regs).
__global__ __launch_bounds__(256) void k_mean(const short* __restrict__ qws,
        const short* __restrict__ kws, const float* __restrict__ c2ws,
        float* __restrict__ attn_out) {
    int b = blockIdx.z;
    int qx = (b & 1) ? (31 - (int)blockIdx.x) : (int)blockIdx.x;
    int q0 = qx*64, k0 = blockIdx.y*64;
    int t = threadIdx.x;
    if (k0 > q0) {
        int r = t >> 2, cq = (t & 3) << 4;
        float4 z4 = {0.f,0.f,0.f,0.f};
        float* dst = attn_out + ((size_t)(b*SS + q0 + r))*SS + k0 + cq;
        #pragma unroll
        for (int j = 0; j < 4; ++j) ((float4*)dst)[j] = z4;
        return;
    }
    __shared__ short Ksm[2][64][72];
    __shared__ float c2s[16][64];
    int w = t>>6, lane = t&63, l15 = lane&15, quad = lane>>4;
    int sr = t>>2, sc = (t&3)<<4;
    #pragma unroll
    for (int i = 0; i < 4; ++i) {
        int idx = t + i*256;
        int hh = idx >> 6, r = idx & 63;
        c2s[hh][r] = c2ws[((size_t)(b*HH+hh))*SS + q0 + r];
    }
    const short* ksrc = kws + (size_t)(b*SS + k0 + sr)*HD + sc;          // + h*64
    const short* qsrc = qws + (size_t)(b*SS + q0 + w*16 + l15)*HD + quad*8;  // + h*64

    // prologue: stage head 0 K, load head 0 Q frags
    {
        const uint4* kp = (const uint4*)ksrc;
        uint4 c = kp[0], d = kp[1];
        *(uint4*)&Ksm[0][sr][sc] = c;  *(uint4*)&Ksm[0][sr][sc+8] = d;
    }
    bf16x8 qc0 = *(const bf16x8*)(qsrc);
    bf16x8 qc1 = *(const bf16x8*)(qsrc + 32);

    const float SC = 0.125f * 1.4426950408889634f;
    int rowg0 = q0 + w*16 + quad*4;
    f32x4 acc[4] = { {0,0,0,0},{0,0,0,0},{0,0,0,0},{0,0,0,0} };

    for (int h = 0; h < HH; ++h) {
        int cur = h & 1;
        __syncthreads();               // Ksm[cur] (and c2s on h=0) ready
        uint4 nka, nkb; bf16x8 nq0, nq1;
        if (h < HH-1) {
            const uint4* kn = (const uint4*)(ksrc + (h+1)*64);
            nka = kn[0]; nkb = kn[1];
            nq0 = *(const bf16x8*)(qsrc + (h+1)*64);
            nq1 = *(const bf16x8*)(qsrc + (h+1)*64 + 32);
        }

        f32x4 c2 = *(const f32x4*)&c2s[h][w*16 + quad*4];
        #pragma unroll
        for (int ns = 0; ns < 4; ++ns) {
            bf16x8 b0 = *(const bf16x8*)&Ksm[cur][ns*16+l15][quad*8];
            bf16x8 b1 = *(const bf16x8*)&Ksm[cur][ns*16+l15][quad*8+32];
            f32x4 s = {0,0,0,0};
            s = __builtin_amdgcn_mfma_f32_16x16x32_bf16(qc0, b0, s, 0, 0, 0);
            s = __builtin_amdgcn_mfma_f32_16x16x32_bf16(qc1, b1, s, 0, 0, 0);
            int col = k0 + ns*16 + l15;
            #pragma unroll
            for (int r = 0; r < 4; ++r) {
                float ex = __builtin_amdgcn_exp2f(s[r]*SC - c2[r]);
                acc[ns][r] += (col <= rowg0 + r) ? ex : 0.0f;
            }
        }

        if (h < HH-1) {
            int nxt = cur ^ 1;
            *(uint4*)&Ksm[nxt][sr][sc]   = nka;  *(uint4*)&Ksm[nxt][sr][sc+8] = nkb;
            qc0 = nq0; qc1 = nq1;
        }
    }
    #pragma unroll
    for (int ns = 0; ns < 4; ++ns)
        #pragma unroll
        for (int r = 0; r < 4; ++r)
            attn_out[((size_t)(b*SS + rowg0 + r))*SS + k0 + ns*16 + l15] =
                acc[ns][r] * 0.0625f;
}

// ---------------- kernel 4: output projection, m97-style ----------------
__global__ __launch_bounds__(256) void k_oproj(const short* __restrict__ zws,
        const short* __restrict__ wto, float* __restrict__ outp) {
    __shared__ short As[128*64];
    __shared__ short Bs[128*64];
    int t = threadIdx.x;
    int m0 = blockIdx.x*128, n0 = blockIdx.y*128;
    int lane = t & 63, l15 = lane & 15, quad = lane >> 4;
    int wm = (t>>6) >> 1, wn = (t>>6) & 1;
    f32x4 acc[4][4];
    #pragma unroll
    for (int i=0;i<4;++i)
        #pragma unroll
        for (int c=0;c<4;++c) acc[i][c] = (f32x4){0,0,0,0};

    for (int k0 = 0; k0 < HD; k0 += 64) {
        __syncthreads();
        #pragma unroll
        for (int j = 0; j < 4; ++j) {
            int c = j*256 + t;
            int row = c >> 3, cg = c & 7;
            GLL(zws + (size_t)(m0+row)*HD + k0 + cg*8, &As[(j*256 + (t & 192))*8]);
            GLL(wto + (size_t)(n0+row)*HD + k0 + cg*8, &Bs[(j*256 + (t & 192))*8]);
        }
        __syncthreads();
        #pragma unroll
        for (int kp = 0; kp < 64; kp += 32)
            #pragma unroll
            for (int i = 0; i < 4; ++i) {
                bf16x8 a = *(const bf16x8*)&As[(wm*64 + i*16 + l15)*64 + kp + quad*8];
                #pragma unroll
                for (int c = 0; c < 4; ++c) {
                    bf16x8 b = *(const bf16x8*)&Bs[(wn*64 + c*16 + l15)*64 + kp + quad*8];
                    acc[i][c] = __builtin_amdgcn_mfma_f32_16x16x32_bf16(a, b, acc[i][c], 0, 0, 0);
                }
            }
    }
    #pragma unroll
    for (int i = 0; i < 4; ++i)
        #pragma unroll
        for (int c = 0; c < 4; ++c)
            #pragma unroll
            for (int r = 0; r < 4; ++r) {
                int row = m0 + wm*64 + i*16 + quad*4 + r;
                int n = n0 + wn*64 + c*16 + l15;
                outp[(size_t)row*EE + n] = acc[i][c][r];
            }
}

extern "C" void kernel_launch(void* const* d_in, const int* in_sizes, int n_in,
                              void* d_out, int out_size, void* d_ws, size_t ws_size,
                              hipStream_t stream) {
    const float* x  = (const float*)d_in[0];
    const float* wq = (const float*)d_in[1];
    const float* wk = (const float*)d_in[2];
    const float* wv = (const float*)d_in[3];
    const float* wo = (const float*)d_in[4];

    short* xbf = (short*)d_ws;                 // 16 MB; reused as z after k_proj
    short* qb  = xbf + QKV_ELEMS;
    short* kb  = qb + QKV_ELEMS;
    short* vtb = kb + QKV_ELEMS;               // V^T [b][h*64+d][pos]
    short* wtq = vtb + QKV_ELEMS;              // 3072x1024 bf16 (n-major)
    short* wto = wtq + (size_t)3*1024*1024;    // 1024x1024 bf16 (n-major)
    float* c2w = (float*)(wto + (size_t)1024*1024);
    short* zb  = xbf;                          // alias: x consumed by k_proj

    float* o = (float*)d_out;
    float* attn_out = o + (size_t)MTOT*EE;

    k_xcast<<<dim3(8192),     256, 0, stream>>>(x, xbf);
    k_wprep<<<dim3(16,64),    256, 0, stream>>>(wq, wk, wv, wo, wtq, wto);
    k_proj <<<dim3(64,24),    256, 0, stream>>>(xbf, wtq, qb);
    k_attnz<<<dim3(8,16,4),   256, 0, stream>>>(qb, kb, vtb, zb, c2w);
    k_mean <<<dim3(32,32,4),  256, 0, stream>>>(qb, kb, c2w, attn_out);
    k_oproj<<<dim3(64,8),     256, 0, stream>>>(zb, wto, o);
}

// Round 6
// 371.478 us; speedup vs baseline: 1.0821x; 1.0821x over previous
//
#include <hip/hip_runtime.h>
#include <stdint.h>

// Attention forward, B=4 S=2048 E=1024 H=16 D=64, causal. Outputs: o fp32 then
// attn.mean(heads) fp32.
//
// R11: recombine the proven pieces of R9/R10. R10's half-fusion doubled VGPR
//      (88->140) and halved occupancy (19.6->10.7%) -> reverted to R9's
//      sequential pair-halves (uniform 34 tiles/block). R10's natural Ps
//      layout (conflict-floor with the [72] pad; R9's XOR was 2.38e7
//      conflicts) -> kept. k_mean keeps R10's K-only-LDS + Q-in-regs.

#define BB 4
#define SS 2048
#define EE 1024
#define HH 16
#define DD 64
#define MTOT (BB*SS)          // 8192
#define HD (HH*DD)            // 1024
#define QKV_ELEMS ((size_t)MTOT*HD)

typedef float f32x4 __attribute__((ext_vector_type(4)));
typedef short bf16x8 __attribute__((ext_vector_type(8)));

#define GLL(g, l) __builtin_amdgcn_global_load_lds( \
    (const __attribute__((address_space(1))) void*)(g), \
    (__attribute__((address_space(3))) void*)(l), 16, 0, 0)

__device__ __forceinline__ short f2bf(float f) {
    unsigned u = __builtin_bit_cast(unsigned, f);
    u += 0x7FFFu + ((u >> 16) & 1u);   // RNE
    return (short)(u >> 16);
}

// ---------------- prep 1: x fp32 -> bf16 ----------------
__global__ __launch_bounds__(256) void k_xcast(const float* __restrict__ x,
                                               short* __restrict__ xbf) {
    int i = blockIdx.x*256 + threadIdx.x;
    float4 f = ((const float4*)x)[i];
    short4 s; s.x=f2bf(f.x); s.y=f2bf(f.y); s.z=f2bf(f.z); s.w=f2bf(f.w);
    ((short4*)xbf)[i] = s;
}

// ---------------- prep 2: W -> bf16, transposed to [n][k] ----------------
__global__ __launch_bounds__(256) void k_wprep(const float* __restrict__ wq,
        const float* __restrict__ wk, const float* __restrict__ wv,
        const float* __restrict__ wo, short* __restrict__ wtq,
        short* __restrict__ wto) {
    __shared__ short Tl[64][72];
    int t = threadIdx.x, x = blockIdx.x, y = blockIdx.y;
    int r4 = t >> 2, c4 = (t & 3) << 4;
    if (y < 48) {
        int which = y >> 4, h = y & 15, e0 = x*64;
        const float* src = (which==0?wq:which==1?wk:wv) + (size_t)h*EE*DD;
        const float* p = src + (size_t)(e0 + r4)*DD + c4;
        #pragma unroll
        for (int j = 0; j < 4; ++j) {
            float4 f = ((const float4*)p)[j];
            Tl[r4][c4+j*4+0]=f2bf(f.x); Tl[r4][c4+j*4+1]=f2bf(f.y);
            Tl[r4][c4+j*4+2]=f2bf(f.z); Tl[r4][c4+j*4+3]=f2bf(f.w);
        }
        __syncthreads();
        size_t nrow = ((size_t)(which*16 + h))*64 + r4;   // d = r4
        #pragma unroll
        for (int i = 0; i < 16; ++i)
            wtq[nrow*1024 + e0 + c4 + i] = Tl[c4+i][r4];
    } else {
        int h = y - 48, e0 = x*64;
        const float* src = wo + (size_t)h*DD*EE;          // [d][e]
        const float* p = src + (size_t)r4*EE + e0 + c4;   // d = r4
        #pragma unroll
        for (int j = 0; j < 4; ++j) {
            float4 f = ((const float4*)p)[j];
            Tl[r4][c4+j*4+0]=f2bf(f.x); Tl[r4][c4+j*4+1]=f2bf(f.y);
            Tl[r4][c4+j*4+2]=f2bf(f.z); Tl[r4][c4+j*4+3]=f2bf(f.w);
        }
        __syncthreads();
        #pragma unroll
        for (int i = 0; i < 16; ++i)
            wto[(size_t)(e0 + r4)*1024 + h*64 + c4 + i] = Tl[c4+i][r4];
    }
}

// ---------------- kernel 1: QKV projection, m97-style ----------------
// grid (64, 24): 128x128 tile, BK=64. Q,K stored [b*S+pos][h*64+d];
// V stored PRE-TRANSPOSED [b][h*64+d][pos].
__global__ __launch_bounds__(256) void k_proj(const short* __restrict__ xbf,
        const short* __restrict__ wtq, short* __restrict__ qkv) {
    __shared__ short As[128*64];
    __shared__ short Bs[128*64];
    int t = threadIdx.x;
    int m0 = blockIdx.x*128, n0 = blockIdx.y*128;
    int lane = t & 63, l15 = lane & 15, quad = lane >> 4;
    int wm = (t>>6) >> 1, wn = (t>>6) & 1;
    f32x4 acc[4][4];
    #pragma unroll
    for (int i=0;i<4;++i)
        #pragma unroll
        for (int c=0;c<4;++c) acc[i][c] = (f32x4){0,0,0,0};

    for (int k0 = 0; k0 < EE; k0 += 64) {
        __syncthreads();
        #pragma unroll
        for (int j = 0; j < 4; ++j) {
            int c = j*256 + t;
            int row = c >> 3, cg = c & 7;
            GLL(xbf + (size_t)(m0+row)*EE + k0 + cg*8, &As[(j*256 + (t & 192))*8]);
            GLL(wtq + (size_t)(n0+row)*EE + k0 + cg*8, &Bs[(j*256 + (t & 192))*8]);
        }
        __syncthreads();
        #pragma unroll
        for (int kp = 0; kp < 64; kp += 32)
            #pragma unroll
            for (int i = 0; i < 4; ++i) {
                bf16x8 a = *(const bf16x8*)&As[(wm*64 + i*16 + l15)*64 + kp + quad*8];
                #pragma unroll
                for (int c = 0; c < 4; ++c) {
                    bf16x8 b = *(const bf16x8*)&Bs[(wn*64 + c*16 + l15)*64 + kp + quad*8];
                    acc[i][c] = __builtin_amdgcn_mfma_f32_16x16x32_bf16(a, b, acc[i][c], 0, 0, 0);
                }
            }
    }
    short* vt = qkv + 2*QKV_ELEMS;
    #pragma unroll
    for (int i = 0; i < 4; ++i)
        #pragma unroll
        for (int c = 0; c < 4; ++c) {
            int n = n0 + wn*64 + c*16 + l15;
            int row = m0 + wm*64 + i*16 + quad*4;
            if (n < 2048) {          // Q or K: [region][b*S+pos][h*64+d]
                #pragma unroll
                for (int r = 0; r < 4; ++r)
                    qkv[(size_t)(n>>10)*QKV_ELEMS + (size_t)(row+r)*HD + (n & 1023)] =
                        f2bf(acc[i][c][r]);
            } else {                 // V: [b][h*64+d][pos], pos contiguous in r
                short4 s4;
                s4.x = f2bf(acc[i][c][0]); s4.y = f2bf(acc[i][c][1]);
                s4.z = f2bf(acc[i][c][2]); s4.w = f2bf(acc[i][c][3]);
                int bb_ = row >> 11, pos = row & 2047;
                *(short4*)&vt[((size_t)bb_*HD + (n - 2048))*SS + pos] = s4;
            }
        }
}

// ---------- kernel 2: z = softmax(QK^T/8) V, no-max; exports c2=log2(l) ----------
// grid (8, 16, 4): each block processes q-tiles {qx, 15-qx} SEQUENTIALLY ->
// uniform 34 k-tile-units per block, one half's state live at a time (~90
// VGPR, 2 blocks/CU). Swapped QK^T (mfma(K,Q)) -> packed b64 P-writes into
// NATURAL Ps layout ([72] pad = conflict floor). T14 prefetch, setprio.
__global__ __launch_bounds__(256) void k_attnz(const short* __restrict__ qws,
        const short* __restrict__ kws, const short* __restrict__ vtg,
        short* __restrict__ zws, float* __restrict__ c2ws) {
    __shared__ short Ks[64][72];
    __shared__ short Vt[64][72];
    __shared__ short Ps[4][32][72];   // per-wave P tile (no barrier needed)
    int t = threadIdx.x;
    int h = blockIdx.y, b = blockIdx.z;
    int w = t>>6, lane = t&63, l15 = lane&15, quad = lane>>4;
    int sr = t>>2, sc = (t&3)<<4;

    const short* ksrc = kws + (size_t)(b*SS + sr)*HD + h*DD + sc;
    const short* vsrc = vtg + ((size_t)b*HD + h*DD + sr)*SS + sc;

    bf16x8 ones;
    #pragma unroll
    for (int i=0;i<8;++i) ones[i] = (short)0x3F80;   // bf16 1.0
    const float SC = 0.125f * 1.4426950408889634f;

    for (int half = 0; half < 2; ++half) {
        int qx = half ? (15 - (int)blockIdx.x) : (int)blockIdx.x;
        int q0 = qx*128;

        bf16x8 qr[2][2];                  // Q fragments, loop-invariant per half
        #pragma unroll
        for (int mf=0; mf<2; ++mf)
            #pragma unroll
            for (int kp=0; kp<2; ++kp)
                qr[mf][kp] = *(const bf16x8*)(qws +
                    (size_t)(b*SS + q0 + w*32 + mf*16 + l15)*HD + h*DD + kp*32 + quad*8);

        f32x4 accz[2][4];
        f32x4 accl[2];
        #pragma unroll
        for (int mf=0;mf<2;++mf) {
            accl[mf] = (f32x4){0,0,0,0};
            #pragma unroll
            for (int c=0;c<4;++c) accz[mf][c] = (f32x4){0,0,0,0};
        }
        int nk = q0/64 + 2;
        int qmax = q0 + w*32 + 31;

        uint4 pk0 = ((const uint4*)ksrc)[0], pk1 = ((const uint4*)ksrc)[1];
        uint4 pv0 = ((const uint4*)vsrc)[0], pv1 = ((const uint4*)vsrc)[1];

        for (int kt = 0; kt < nk; ++kt) {
            int k0 = kt*64;
            __syncthreads();               // prior compute done reading LDS
            *(uint4*)&Ks[sr][sc]   = pk0;  *(uint4*)&Ks[sr][sc+8] = pk1;
            *(uint4*)&Vt[sr][sc]   = pv0;  *(uint4*)&Vt[sr][sc+8] = pv1;
            __syncthreads();               // tile ready
            if (kt+1 < nk) {               // T14: issue next tile under compute
                const uint4* kn = (const uint4*)(ksrc + (size_t)(k0+64)*HD);
                const uint4* vn = (const uint4*)(vsrc + (k0+64));
                pk0=kn[0]; pk1=kn[1]; pv0=vn[0]; pv1=vn[1];
            }
            if (k0 > qmax) continue;       // fully masked for this wave

            // QK^T swapped: s[mf][c] -> col(l15)=q-row(mf*16+l15),
            // row(quad*4+r)=k-pos(c*16+quad*4+r)
            f32x4 s[2][4];
            #pragma unroll
            for (int mf=0;mf<2;++mf)
                #pragma unroll
                for (int c=0;c<4;++c) s[mf][c] = (f32x4){0,0,0,0};
            __builtin_amdgcn_s_setprio(1);
            #pragma unroll
            for (int c=0;c<4;++c)
                #pragma unroll
                for (int kp=0;kp<2;++kp) {
                    bf16x8 aK = *(const bf16x8*)&Ks[c*16+l15][kp*32+quad*8];
                    s[0][c] = __builtin_amdgcn_mfma_f32_16x16x32_bf16(aK, qr[0][kp], s[0][c], 0, 0, 0);
                    s[1][c] = __builtin_amdgcn_mfma_f32_16x16x32_bf16(aK, qr[1][kp], s[1][c], 0, 0, 0);
                }
            __builtin_amdgcn_s_setprio(0);
            // P epilogue: 4 consecutive k per lane -> packed b64 write, natural layout.
            #pragma unroll
            for (int mf=0;mf<2;++mf) {
                int qg = q0 + w*32 + mf*16 + l15;
                #pragma unroll
                for (int c=0;c<4;++c) {
                    int kb = k0 + c*16 + quad*4;
                    short4 s4;
                    #pragma unroll
                    for (int r=0;r<4;++r) {
                        float p_ = (kb + r <= qg) ? __builtin_amdgcn_exp2f(s[mf][c][r]*SC) : 0.0f;
                        ((short*)&s4)[r] = f2bf(p_);
                    }
                    *(short4*)&Ps[w][mf*16 + l15][c*16 + quad*4] = s4;
                }
            }
            // Ps is wave-private: HW lgkmcnt ordering suffices, no barrier.
            __builtin_amdgcn_s_setprio(1);
            #pragma unroll
            for (int kp=0;kp<2;++kp) {
                bf16x8 pa0 = *(const bf16x8*)&Ps[w][l15][kp*32+quad*8];
                bf16x8 pa1 = *(const bf16x8*)&Ps[w][16+l15][kp*32+quad*8];
                #pragma unroll
                for (int cc=0;cc<4;++cc) {
                    bf16x8 vb = *(const bf16x8*)&Vt[cc*16+l15][kp*32+quad*8];
                    accz[0][cc] = __builtin_amdgcn_mfma_f32_16x16x32_bf16(pa0, vb, accz[0][cc], 0, 0, 0);
                    accz[1][cc] = __builtin_amdgcn_mfma_f32_16x16x32_bf16(pa1, vb, accz[1][cc], 0, 0, 0);
                }
                accl[0] = __builtin_amdgcn_mfma_f32_16x16x32_bf16(pa0, ones, accl[0], 0, 0, 0);
                accl[1] = __builtin_amdgcn_mfma_f32_16x16x32_bf16(pa1, ones, accl[1], 0, 0, 0);
            }
            __builtin_amdgcn_s_setprio(0);
        }
        #pragma unroll
        for (int mf=0;mf<2;++mf) {
            float il[4];
            #pragma unroll
            for (int r=0;r<4;++r) il[r] = 1.0f / accl[mf][r];
            #pragma unroll
            for (int cc=0;cc<4;++cc)
                #pragma unroll
                for (int r=0;r<4;++r) {
                    int row = q0 + w*32 + mf*16 + quad*4 + r;
                    zws[(size_t)(b*SS+row)*HD + h*DD + cc*16 + l15] = f2bf(accz[mf][cc][r]*il[r]);
                }
            if (l15 == 0) {
                size_t base = ((size_t)(b*HH+h))*SS + q0 + w*32 + mf*16 + quad*4;
                #pragma unroll
                for (int r=0;r<4;++r)
                    c2ws[base+r] = __log2f(accl[mf][r]);
            }
        }
    }
}

// ---------------- kernel 3: attn mean over heads ----------------
// grid (32, 32, 4). Upper-triangle blocks write zeros. Only K staged in LDS
// (each wave reads just its own 16 Q rows -> Q frags prefetched to regs).
__global__ __launch_bounds__(256) void k_mean(const short* __restrict__ qws,
        const short* __restrict__ kws, const float* __restrict__ c2ws,
        float* __restrict__ attn_out) {
    int b = blockIdx.z;
    int qx = (b & 1) ? (31 - (int)blockIdx.x) : (int)blockIdx.x;
    int q0 = qx*64, k0 = blockIdx.y*64;
    int t = threadIdx.x;
    if (k0 > q0) {
        int r = t >> 2, cq = (t & 3) << 4;
        float4 z4 = {0.f,0.f,0.f,0.f};
        float* dst = attn_out + ((size_t)(b*SS + q0 + r))*SS + k0 + cq;
        #pragma unroll
        for (int j = 0; j < 4; ++j) ((float4*)dst)[j] = z4;
        return;
    }
    __shared__ short Ksm[2][64][72];
    __shared__ float c2s[16][64];
    int w = t>>6, lane = t&63, l15 = lane&15, quad = lane>>4;
    int sr = t>>2, sc = (t&3)<<4;
    #pragma unroll
    for (int i = 0; i < 4; ++i) {
        int idx = t + i*256;
        int hh = idx >> 6, r = idx & 63;
        c2s[hh][r] = c2ws[((size_t)(b*HH+hh))*SS + q0 + r];
    }
    const short* ksrc = kws + (size_t)(b*SS + k0 + sr)*HD + sc;          // + h*64
    const short* qsrc = qws + (size_t)(b*SS + q0 + w*16 + l15)*HD + quad*8;  // + h*64

    // prologue: stage head 0 K, load head 0 Q frags
    {
        const uint4* kp = (const uint4*)ksrc;
        uint4 c = kp[0], d = kp[1];
        *(uint4*)&Ksm[0][sr][sc] = c;  *(uint4*)&Ksm[0][sr][sc+8] = d;
    }
    bf16x8 qc0 = *(const bf16x8*)(qsrc);
    bf16x8 qc1 = *(const bf16x8*)(qsrc + 32);

    const float SC = 0.125f * 1.4426950408889634f;
    int rowg0 = q0 + w*16 + quad*4;
    f32x4 acc[4] = { {0,0,0,0},{0,0,0,0},{0,0,0,0},{0,0,0,0} };

    for (int h = 0; h < HH; ++h) {
        int cur = h & 1;
        __syncthreads();               // Ksm[cur] (and c2s on h=0) ready
        uint4 nka, nkb; bf16x8 nq0, nq1;
        if (h < HH-1) {
            const uint4* kn = (const uint4*)(ksrc + (h+1)*64);
            nka = kn[0]; nkb = kn[1];
            nq0 = *(const bf16x8*)(qsrc + (h+1)*64);
            nq1 = *(const bf16x8*)(qsrc + (h+1)*64 + 32);
        }

        f32x4 c2 = *(const f32x4*)&c2s[h][w*16 + quad*4];
        #pragma unroll
        for (int ns = 0; ns < 4; ++ns) {
            bf16x8 b0 = *(const bf16x8*)&Ksm[cur][ns*16+l15][quad*8];
            bf16x8 b1 = *(const bf16x8*)&Ksm[cur][ns*16+l15][quad*8+32];
            f32x4 s = {0,0,0,0};
            s = __builtin_amdgcn_mfma_f32_16x16x32_bf16(qc0, b0, s, 0, 0, 0);
            s = __builtin_amdgcn_mfma_f32_16x16x32_bf16(qc1, b1, s, 0, 0, 0);
            int col = k0 + ns*16 + l15;
            #pragma unroll
            for (int r = 0; r < 4; ++r) {
                float ex = __builtin_amdgcn_exp2f(s[r]*SC - c2[r]);
                acc[ns][r] += (col <= rowg0 + r) ? ex : 0.0f;
            }
        }

        if (h < HH-1) {
            int nxt = cur ^ 1;
            *(uint4*)&Ksm[nxt][sr][sc]   = nka;  *(uint4*)&Ksm[nxt][sr][sc+8] = nkb;
            qc0 = nq0; qc1 = nq1;
        }
    }
    #pragma unroll
    for (int ns = 0; ns < 4; ++ns)
        #pragma unroll
        for (int r = 0; r < 4; ++r)
            attn_out[((size_t)(b*SS + rowg0 + r))*SS + k0 + ns*16 + l15] =
                acc[ns][r] * 0.0625f;
}

// ---------------- kernel 4: output projection, m97-style ----------------
__global__ __launch_bounds__(256) void k_oproj(const short* __restrict__ zws,
        const short* __restrict__ wto, float* __restrict__ outp) {
    __shared__ short As[128*64];
    __shared__ short Bs[128*64];
    int t = threadIdx.x;
    int m0 = blockIdx.x*128, n0 = blockIdx.y*128;
    int lane = t & 63, l15 = lane & 15, quad = lane >> 4;
    int wm = (t>>6) >> 1, wn = (t>>6) & 1;
    f32x4 acc[4][4];
    #pragma unroll
    for (int i=0;i<4;++i)
        #pragma unroll
        for (int c=0;c<4;++c) acc[i][c] = (f32x4){0,0,0,0};

    for (int k0 = 0; k0 < HD; k0 += 64) {
        __syncthreads();
        #pragma unroll
        for (int j = 0; j < 4; ++j) {
            int c = j*256 + t;
            int row = c >> 3, cg = c & 7;
            GLL(zws + (size_t)(m0+row)*HD + k0 + cg*8, &As[(j*256 + (t & 192))*8]);
            GLL(wto + (size_t)(n0+row)*HD + k0 + cg*8, &Bs[(j*256 + (t & 192))*8]);
        }
        __syncthreads();
        #pragma unroll
        for (int kp = 0; kp < 64; kp += 32)
            #pragma unroll
            for (int i = 0; i < 4; ++i) {
                bf16x8 a = *(const bf16x8*)&As[(wm*64 + i*16 + l15)*64 + kp + quad*8];
                #pragma unroll
                for (int c = 0; c < 4; ++c) {
                    bf16x8 b = *(const bf16x8*)&Bs[(wn*64 + c*16 + l15)*64 + kp + quad*8];
                    acc[i][c] = __builtin_amdgcn_mfma_f32_16x16x32_bf16(a, b, acc[i][c], 0, 0, 0);
                }
            }
    }
    #pragma unroll
    for (int i = 0; i < 4; ++i)
        #pragma unroll
        for (int c = 0; c < 4; ++c)
            #pragma unroll
            for (int r = 0; r < 4; ++r) {
                int row = m0 + wm*64 + i*16 + quad*4 + r;
                int n = n0 + wn*64 + c*16 + l15;
                outp[(size_t)row*EE + n] = acc[i][c][r];
            }
}

extern "C" void kernel_launch(void* const* d_in, const int* in_sizes, int n_in,
                              void* d_out, int out_size, void* d_ws, size_t ws_size,
                              hipStream_t stream) {
    const float* x  = (const float*)d_in[0];
    const float* wq = (const float*)d_in[1];
    const float* wk = (const float*)d_in[2];
    const float* wv = (const float*)d_in[3];
    const float* wo = (const float*)d_in[4];

    short* xbf = (short*)d_ws;                 // 16 MB; reused as z after k_proj
    short* qb  = xbf + QKV_ELEMS;
    short* kb  = qb + QKV_ELEMS;
    short* vtb = kb + QKV_ELEMS;               // V^T [b][h*64+d][pos]
    short* wtq = vtb + QKV_ELEMS;              // 3072x1024 bf16 (n-major)
    short* wto = wtq + (size_t)3*1024*1024;    // 1024x1024 bf16 (n-major)
    float* c2w = (float*)(wto + (size_t)1024*1024);
    short* zb  = xbf;                          // alias: x consumed by k_proj

    float* o = (float*)d_out;
    float* attn_out = o + (size_t)MTOT*EE;

    k_xcast<<<dim3(8192),     256, 0, stream>>>(x, xbf);
    k_wprep<<<dim3(16,64),    256, 0, stream>>>(wq, wk, wv, wo, wtq, wto);
    k_proj <<<dim3(64,24),    256, 0, stream>>>(xbf, wtq, qb);
    k_attnz<<<dim3(8,16,4),   256, 0, stream>>>(qb, kb, vtb, zb, c2w);
    k_mean <<<dim3(32,32,4),  256, 0, stream>>>(qb, kb, c2w, attn_out);
    k_oproj<<<dim3(64,8),     256, 0, stream>>>(zb, wto, o);
}